// Round 3
// baseline (116.440 us; speedup 1.0000x reference)
//
#include <hip/hip_runtime.h>

// LNCC loss: I,J [16,1,768,768] f32 -> out [16] f32
// Fully streaming wave-autonomous design: no LDS tiles, no barriers.
// Each wave owns 64 columns (56 outputs + 8 halo) and slides a 9-row
// window down a 32-row segment. Vertical sums of the 5 channels live in
// registers (8-deep ring + add-compute-subtract); horizontal 9-sums via
// a 4-shuffle tree per channel.

constexpr int BATCH = 16;
constexpr int H = 768;
constexpr int W = 768;
constexpr float INV_WS = 1.0f / 81.0f;
constexpr float EPS = 3.0590232050182579e-07f;   // exp(-15)

constexpr int OUTW = 56;                          // output cols per wave
constexpr int NSTRIPE = (W + OUTW - 1) / OUTW;    // 14
constexpr int SEG = 32;                           // output rows per wave task
constexpr int NSEG = H / SEG;                     // 24
constexpr int WPB = 4;                            // waves per block
constexpr int NTHREADS = WPB * 64;                // 256
constexpr int BLOCKS_PER_IMG = (NSTRIPE * NSEG) / WPB;  // 336/4 = 84

__global__ void zero_acc_kernel(float* acc) {
    if (threadIdx.x < BATCH) acc[threadIdx.x] = 0.0f;
}

__device__ __forceinline__ float hsum9(float v) {
    // out[l] = sum v[l .. l+8]; valid for lanes 0..55
    float a = v + __shfl_down(v, 1, 64) + __shfl_down(v, 2, 64);
    return a + __shfl_down(a, 3, 64) + __shfl_down(a, 6, 64);
}

__launch_bounds__(NTHREADS, 6)
__global__ void lncc_stream(const float* __restrict__ gI, const float* __restrict__ gJ,
                            float* __restrict__ acc)
{
    const int lane = threadIdx.x & 63;
    const int w    = blockIdx.x * WPB + (threadIdx.x >> 6);   // 0..335 within image
    const int b    = blockIdx.y;                              // image (block-uniform)
    const int s    = w % NSTRIPE;                             // column stripe
    const int g    = w / NSTRIPE;                             // row segment

    // column this lane owns (includes 4-wide halo on each side of the stripe)
    const int c  = s * OUTW - 4 + lane;
    const float fc = ((unsigned)c < (unsigned)W) ? 1.0f : 0.0f;  // zero-pad mask
    const int cc = min(max(c, 0), W - 1);                        // safe address

    const float* __restrict__ Ib = gI + (size_t)b * (H * W);
    const float* __restrict__ Jb = gJ + (size_t)b * (H * W);

    const int r0 = g * SEG;

    // 8-deep ring buffer of raw I/J pixels (statically indexed via unroll).
    // Invariant at the top of inner iteration for output row r:
    //   s* = sum over input rows [r-4, r+3] (8 rows); ring holds those rows.
    float rI[8], rJ[8];
    float sI = 0.f, sJ = 0.f, sII = 0.f, sJJ = 0.f, sIJ = 0.f;

    // ---- warm-up: rows r0-4 .. r0+3 (zero above the image) ----
    #pragma unroll
    for (int k = 0; k < 8; ++k) {
        const int r = r0 - 4 + k;                 // <= 739, never >= H here
        float vi = 0.f, vj = 0.f;
        if (r >= 0) {
            const int idx = r * W + cc;
            vi = Ib[idx] * fc;
            vj = Jb[idx] * fc;
        }
        rI[k] = vi; rJ[k] = vj;
        sI += vi; sJ += vj;
        sII = fmaf(vi, vi, sII);
        sJJ = fmaf(vj, vj, sJJ);
        sIJ = fmaf(vi, vj, sIJ);
    }

    const bool live = (lane < OUTW) && (s * OUTW + lane < W);
    float accum = 0.f;
    int idx = (r0 + 4) * W + cc;

    // ---- main loop: 32 output rows, unrolled by 8 so ring index is static ----
    #pragma unroll 1
    for (int i0 = 0; i0 < SEG; i0 += 8) {
        #pragma unroll
        for (int j = 0; j < 8; ++j) {
            const int r = r0 + 4 + i0 + j;        // incoming input row (= out_row + 4)
            float vi = 0.f, vj = 0.f;
            if (r < H) {                          // zero below the image
                vi = Ib[idx] * fc;
                vj = Jb[idx] * fc;
            }
            idx += W;

            // 9-row window sums: t* = s* + contrib(incoming row)
            const float tI  = sI + vi;
            const float tJ  = sJ + vj;
            const float tII = fmaf(vi, vi, sII);
            const float tJJ = fmaf(vj, vj, sJJ);
            const float tIJ = fmaf(vi, vj, sIJ);

            // rotate window: drop oldest row, keep 8 rows for next iteration
            const float oi = rI[j], oj = rJ[j];
            rI[j] = vi; rJ[j] = vj;
            sI  = tI - oi;
            sJ  = tJ - oj;
            sII = fmaf(oi, -oi, tII);
            sJJ = fmaf(oj, -oj, tJJ);
            sIJ = fmaf(oi, -oj, tIJ);

            // horizontal 9-sums: lane l -> output column s*56 + l
            const float hI  = hsum9(tI);
            const float hJ  = hsum9(tJ);
            const float hII = hsum9(tII);
            const float hJJ = hsum9(tJJ);
            const float hIJ = hsum9(tIJ);

            // cross = IJ - I*J/81 ; var = X2 - X^2/81  (algebraically = reference)
            const float cross = fmaf(-hI * INV_WS, hJ, hIJ);
            const float Ivar  = fmaf(-hI * INV_WS, hI, hII);
            const float Jvar  = fmaf(-hJ * INV_WS, hJ, hJJ);
            float prod = Ivar * Jvar;
            float num  = cross * cross;
            if (!(prod > EPS)) { prod = 1.0f; num = 1.0f; }
            const float den = prod + EPS;
            float inv;
            asm("v_rcp_f32 %0, %1" : "=v"(inv) : "v"(den));
            accum += live ? num * inv : 0.0f;
        }
    }

    // ---- wave reduction + one atomic per wave ----
    #pragma unroll
    for (int off = 32; off > 0; off >>= 1)
        accum += __shfl_xor(accum, off, 64);
    if (lane == 0) atomicAdd(&acc[b], accum);
}

__global__ void finalize_kernel(const float* __restrict__ acc, float* __restrict__ out) {
    if (threadIdx.x < BATCH)
        out[threadIdx.x] = 1.0f - acc[threadIdx.x] * (1.0f / (float)(H * W));
}

extern "C" void kernel_launch(void* const* d_in, const int* in_sizes, int n_in,
                              void* d_out, int out_size, void* d_ws, size_t ws_size,
                              hipStream_t stream) {
    const float* I = (const float*)d_in[0];
    const float* J = (const float*)d_in[1];
    float* out = (float*)d_out;
    float* acc = (float*)d_ws;

    zero_acc_kernel<<<1, 64, 0, stream>>>(acc);

    dim3 grid(BLOCKS_PER_IMG, BATCH);   // 84 x 16 = 1344 blocks, 5376 waves
    lncc_stream<<<grid, NTHREADS, 0, stream>>>(I, J, acc);

    finalize_kernel<<<1, 64, 0, stream>>>(acc, out);
}

// Round 4
// 116.123 us; speedup vs baseline: 1.0027x; 1.0027x over previous
//
#include <hip/hip_runtime.h>

// LNCC loss: I,J [16,1,768,768] f32 -> out [16] f32
// Wave-autonomous streaming: no LDS, no barriers. Each wave owns 64 columns
// (56 outputs + 8 halo) and slides a 9-row window down a 32-row segment.
// Ring buffer of the last 8 raw rows kept in 16 NAMED registers (macro-expanded
// static indexing — an indexed array was demoted to scratch: 44.7 MB of
// WRITE_SIZE and a 10% VALUBusy latency collapse in round 3).

constexpr int BATCH = 16;
constexpr int H = 768;
constexpr int W = 768;
constexpr float INV_WS = 1.0f / 81.0f;
constexpr float EPS = 3.0590232050182579e-07f;   // exp(-15)

constexpr int OUTW = 56;                          // output cols per wave
constexpr int NSTRIPE = (W + OUTW - 1) / OUTW;    // 14
constexpr int SEG = 32;                           // output rows per wave task
constexpr int NSEG = H / SEG;                     // 24
constexpr int WPB = 4;                            // waves per block
constexpr int NTHREADS = WPB * 64;                // 256
constexpr int BLOCKS_PER_IMG = (NSTRIPE * NSEG) / WPB;  // 84

__global__ void zero_acc_kernel(float* acc) {
    if (threadIdx.x < BATCH) acc[threadIdx.x] = 0.0f;
}

__device__ __forceinline__ float hsum9(float v) {
    // out[l] = sum v[l .. l+8]; valid for lanes 0..55 (depth-2 bpermute tree)
    float a = v + __shfl_down(v, 1, 64) + __shfl_down(v, 2, 64);
    return a + __shfl_down(a, 3, 64) + __shfl_down(a, 6, 64);
}

__launch_bounds__(NTHREADS, 6)
__global__ void lncc_stream(const float* __restrict__ gI, const float* __restrict__ gJ,
                            float* __restrict__ acc)
{
    const int lane = threadIdx.x & 63;
    const int w    = blockIdx.x * WPB + (threadIdx.x >> 6);   // 0..335 within image
    const int b    = blockIdx.y;                              // image (block-uniform)
    const int s    = w % NSTRIPE;                             // column stripe
    const int g    = w / NSTRIPE;                             // row segment

    const int c  = s * OUTW - 4 + lane;                       // owned column (with halo)
    const float fc = ((unsigned)c < (unsigned)W) ? 1.0f : 0.0f;
    const int cc = min(max(c, 0), W - 1);

    const float* __restrict__ Ib = gI + (size_t)b * (H * W);
    const float* __restrict__ Jb = gJ + (size_t)b * (H * W);

    const int r0 = g * SEG;

    // 8-deep ring in NAMED registers. Invariant at top of each row step for
    // output row r: s* = sum over input rows [r-4, r+3]; ring holds those rows.
    float rI0, rI1, rI2, rI3, rI4, rI5, rI6, rI7;
    float rJ0, rJ1, rJ2, rJ3, rJ4, rJ5, rJ6, rJ7;
    float sI = 0.f, sJ = 0.f, sII = 0.f, sJJ = 0.f, sIJ = 0.f;

#define WARM(K)                                                         \
    {                                                                   \
        const int r = r0 - 4 + K;                                       \
        float vi = 0.f, vj = 0.f;                                       \
        if (r >= 0) {                                                   \
            const int id = r * W + cc;                                  \
            vi = Ib[id] * fc;                                           \
            vj = Jb[id] * fc;                                           \
        }                                                               \
        rI##K = vi; rJ##K = vj;                                         \
        sI += vi; sJ += vj;                                             \
        sII = fmaf(vi, vi, sII);                                        \
        sJJ = fmaf(vj, vj, sJJ);                                        \
        sIJ = fmaf(vi, vj, sIJ);                                        \
    }
    WARM(0) WARM(1) WARM(2) WARM(3) WARM(4) WARM(5) WARM(6) WARM(7)
#undef WARM

    const bool live = (lane < OUTW) && (s * OUTW + lane < W);
    float accum = 0.f;
    int idx = (r0 + 4) * W + cc;

#define ROW(J)                                                          \
    {                                                                   \
        const int r = rbase + J;              /* incoming input row */  \
        float vi = 0.f, vj = 0.f;                                       \
        if (r < H) { vi = Ib[idx] * fc; vj = Jb[idx] * fc; }            \
        idx += W;                                                       \
        /* 9-row sums: t* = s* + incoming */                            \
        const float tI  = sI + vi;                                      \
        const float tJ  = sJ + vj;                                      \
        const float tII = fmaf(vi, vi, sII);                            \
        const float tJJ = fmaf(vj, vj, sJJ);                            \
        const float tIJ = fmaf(vi, vj, sIJ);                            \
        /* rotate: drop oldest, keep 8 rows */                          \
        const float oi = rI##J, oj = rJ##J;                             \
        rI##J = vi; rJ##J = vj;                                         \
        sI  = tI - oi;                                                  \
        sJ  = tJ - oj;                                                  \
        sII = fmaf(oi, -oi, tII);                                       \
        sJJ = fmaf(oj, -oj, tJJ);                                       \
        sIJ = fmaf(oi, -oj, tIJ);                                       \
        /* horizontal 9-sums: lane l -> output column s*56 + l */       \
        const float hI  = hsum9(tI);                                    \
        const float hJ  = hsum9(tJ);                                    \
        const float hII = hsum9(tII);                                   \
        const float hJJ = hsum9(tJJ);                                   \
        const float hIJ = hsum9(tIJ);                                   \
        const float u = -hI * INV_WS;                                   \
        const float cross = fmaf(u, hJ, hIJ);                           \
        const float Ivar  = fmaf(u, hI, hII);                           \
        const float Jvar  = fmaf(-hJ * INV_WS, hJ, hJJ);                \
        float prod = Ivar * Jvar;                                       \
        float num  = cross * cross;                                     \
        if (!(prod > EPS)) { prod = 1.0f; num = 1.0f; }                 \
        float inv;                                                      \
        asm("v_rcp_f32 %0, %1" : "=v"(inv) : "v"(prod + EPS));          \
        accum += live ? num * inv : 0.0f;                               \
    }

    #pragma unroll 1
    for (int i0 = 0; i0 < SEG; i0 += 8) {
        const int rbase = r0 + 4 + i0;
        ROW(0) ROW(1) ROW(2) ROW(3) ROW(4) ROW(5) ROW(6) ROW(7)
    }
#undef ROW

    // ---- wave reduction + one atomic per wave ----
    #pragma unroll
    for (int off = 32; off > 0; off >>= 1)
        accum += __shfl_xor(accum, off, 64);
    if (lane == 0) atomicAdd(&acc[b], accum);
}

__global__ void finalize_kernel(const float* __restrict__ acc, float* __restrict__ out) {
    if (threadIdx.x < BATCH)
        out[threadIdx.x] = 1.0f - acc[threadIdx.x] * (1.0f / (float)(H * W));
}

extern "C" void kernel_launch(void* const* d_in, const int* in_sizes, int n_in,
                              void* d_out, int out_size, void* d_ws, size_t ws_size,
                              hipStream_t stream) {
    const float* I = (const float*)d_in[0];
    const float* J = (const float*)d_in[1];
    float* out = (float*)d_out;
    float* acc = (float*)d_ws;

    zero_acc_kernel<<<1, 64, 0, stream>>>(acc);

    dim3 grid(BLOCKS_PER_IMG, BATCH);   // 84 x 16 = 1344 blocks, 5376 waves
    lncc_stream<<<grid, NTHREADS, 0, stream>>>(I, J, acc);

    finalize_kernel<<<1, 64, 0, stream>>>(acc, out);
}

// Round 5
// 65.392 us; speedup vs baseline: 1.7807x; 1.7758x over previous
//
#include <hip/hip_runtime.h>

// LNCC loss: I,J [16,1,768,768] f32 -> out [16] f32
// Thread-autonomous design: each thread owns 4 adjacent output columns and
// redundantly computes all 12 colsums it needs (4 own + 4 halo each side).
// NO shuffles, NO LDS, NO barriers, NO register ring: the vertical 9-row
// slide re-loads the outgoing row (L2-warm, loaded 8 rows earlier).
// All loads are aligned float4; edges handled by clamp-address + mask-mul.

constexpr int BATCH = 16;
constexpr int H = 768;
constexpr int W = 768;
constexpr float INV_WS = 1.0f / 81.0f;
constexpr float EPS = 3.0590232050182579e-07f;   // exp(-15)

constexpr int COLS = 4;                    // output cols per thread
constexpr int STRIPW = 64 * COLS;          // 256 cols per wave
constexpr int NSTRIP = W / STRIPW;         // 3
constexpr int SEG = 16;                    // output rows per wave task
constexpr int NSEG = H / SEG;              // 48
constexpr int WPB = 3;                     // waves per block
constexpr int NTHREADS = WPB * 64;         // 192
constexpr int BLOCKS_PER_IMG = (NSTRIP * NSEG) / WPB;   // 48

__global__ void zero_acc_kernel(float* acc) {
    if (threadIdx.x < BATCH) acc[threadIdx.x] = 0.0f;
}

__launch_bounds__(NTHREADS, 2)
__global__ void lncc4(const float* __restrict__ gI, const float* __restrict__ gJ,
                      float* __restrict__ acc)
{
    const int lane  = threadIdx.x & 63;
    const int wv    = blockIdx.x * WPB + (threadIdx.x >> 6);  // 0..143 in image
    const int b     = blockIdx.y;
    const int strip = wv % NSTRIP;
    const int seg   = wv / NSTRIP;
    const int r0    = seg * SEG;
    const int cbase = strip * STRIPW + lane * COLS;           // first owned col

    // three 16B-aligned 4-col chunks: [cbase-4], [cbase], [cbase+4]
    const float m0 = (cbase - 4 >= 0) ? 1.0f : 0.0f;   // left image edge
    const float m2 = (cbase + 8 <= W) ? 1.0f : 0.0f;   // right image edge
    const int ca0 = max(cbase - 4, 0);
    const int ca1 = cbase;
    const int ca2 = min(cbase + 4, W - 4);

    const float* __restrict__ Ib = gI + (size_t)b * (H * W);
    const float* __restrict__ Jb = gJ + (size_t)b * (H * W);

    // 8-row partial colsums of the 5 channels for the 12 columns.
    float cs0[12], cs1[12], cs2[12], cs3[12], cs4[12];
    #pragma unroll
    for (int x = 0; x < 12; ++x) {
        cs0[x] = 0.f; cs1[x] = 0.f; cs2[x] = 0.f; cs3[x] = 0.f; cs4[x] = 0.f;
    }

// 12 masked floats from one row (3 aligned float4 loads)
#define LD12(dst, base, roff, rm)                                         \
    {                                                                     \
        const float4 q0 = *(const float4*)((base) + (roff) + ca0);        \
        const float4 q1 = *(const float4*)((base) + (roff) + ca1);        \
        const float4 q2 = *(const float4*)((base) + (roff) + ca2);        \
        const float f0 = (rm) * m0, f1 = (rm), f2 = (rm) * m2;            \
        dst[0] = q0.x * f0; dst[1] = q0.y * f0;                           \
        dst[2] = q0.z * f0; dst[3] = q0.w * f0;                           \
        dst[4] = q1.x * f1; dst[5] = q1.y * f1;                           \
        dst[6] = q1.z * f1; dst[7] = q1.w * f1;                           \
        dst[8] = q2.x * f2; dst[9] = q2.y * f2;                           \
        dst[10] = q2.z * f2; dst[11] = q2.w * f2;                         \
    }

    // ---- warm-up: rows r0-4 .. r0+3 (zero above the image) ----
    #pragma unroll
    for (int k = 0; k < 8; ++k) {
        const int r = r0 - 4 + k;                 // <= 747, never >= H
        const float rm = (r >= 0) ? 1.0f : 0.0f;
        const int roff = max(r, 0) * W;
        float vi[12], vj[12];
        LD12(vi, Ib, roff, rm)
        LD12(vj, Jb, roff, rm)
        #pragma unroll
        for (int x = 0; x < 12; ++x) {
            cs0[x] += vi[x];
            cs1[x] += vj[x];
            cs2[x] = fmaf(vi[x], vi[x], cs2[x]);
            cs3[x] = fmaf(vj[x], vj[x], cs3[x]);
            cs4[x] = fmaf(vi[x], vj[x], cs4[x]);
        }
    }

    float accum = 0.0f;

    // ---- main loop: one output row per iteration ----
    #pragma unroll 1
    for (int r = r0; r < r0 + SEG; ++r) {
        const int rin  = r + 4;                    // entering window
        const int rout = r - 4;                    // leaving window
        const float rmi = (rin < H)   ? 1.0f : 0.0f;
        const float rmo = (rout >= 0) ? 1.0f : 0.0f;
        const int oin  = min(rin, H - 1) * W;
        const int oout = max(rout, 0) * W;

        float vi[12], vj[12], oi[12], oj[12];
        LD12(vi, Ib, oin,  rmi)
        LD12(vj, Jb, oin,  rmi)
        LD12(oi, Ib, oout, rmo)
        LD12(oj, Jb, oout, rmo)

        // 9-row sums t = cs + incoming; cs <- t - outgoing (8-row for next r)
        float t0[12], t1[12], t2[12], t3[12], t4[12];
        #pragma unroll
        for (int x = 0; x < 12; ++x) {
            t0[x] = cs0[x] + vi[x];
            t1[x] = cs1[x] + vj[x];
            t2[x] = fmaf(vi[x], vi[x], cs2[x]);
            t3[x] = fmaf(vj[x], vj[x], cs3[x]);
            t4[x] = fmaf(vi[x], vj[x], cs4[x]);
            cs0[x] = t0[x] - oi[x];
            cs1[x] = t1[x] - oj[x];
            cs2[x] = fmaf(oi[x], -oi[x], t2[x]);
            cs3[x] = fmaf(oj[x], -oj[x], t3[x]);
            cs4[x] = fmaf(oi[x], -oj[x], t4[x]);
        }

        // horizontal 9-sums for the 4 owned columns (sliding within registers)
#define HSUM(T, h)                                                        \
        {                                                                 \
            float s_ = T[0] + T[1] + T[2] + T[3] + T[4] + T[5] + T[6]     \
                     + T[7] + T[8];                                       \
            h[0] = s_;                                                    \
            s_ += T[9]  - T[0]; h[1] = s_;                                \
            s_ += T[10] - T[1]; h[2] = s_;                                \
            s_ += T[11] - T[2]; h[3] = s_;                                \
        }
        float hI[4], hJ[4], hII[4], hJJ[4], hIJ[4];
        HSUM(t0, hI)
        HSUM(t1, hJ)
        HSUM(t2, hII)
        HSUM(t3, hJJ)
        HSUM(t4, hIJ)
#undef HSUM

        #pragma unroll
        for (int e = 0; e < 4; ++e) {
            const float u = -hI[e] * INV_WS;
            const float cross = fmaf(u, hJ[e], hIJ[e]);
            const float Ivar  = fmaf(u, hI[e], hII[e]);
            const float Jvar  = fmaf(-hJ[e] * INV_WS, hJ[e], hJJ[e]);
            float prod = Ivar * Jvar;
            float num  = cross * cross;
            if (!(prod > EPS)) { prod = 1.0f; num = 1.0f; }
            float inv_;
            asm("v_rcp_f32 %0, %1" : "=v"(inv_) : "v"(prod + EPS));
            accum += num * inv_;
        }
    }
#undef LD12

    // ---- wave reduction + one atomic per wave ----
    #pragma unroll
    for (int off = 32; off > 0; off >>= 1)
        accum += __shfl_xor(accum, off, 64);
    if (lane == 0) atomicAdd(&acc[b], accum);
}

__global__ void finalize_kernel(const float* __restrict__ acc, float* __restrict__ out) {
    if (threadIdx.x < BATCH)
        out[threadIdx.x] = 1.0f - acc[threadIdx.x] * (1.0f / (float)(H * W));
}

extern "C" void kernel_launch(void* const* d_in, const int* in_sizes, int n_in,
                              void* d_out, int out_size, void* d_ws, size_t ws_size,
                              hipStream_t stream) {
    const float* I = (const float*)d_in[0];
    const float* J = (const float*)d_in[1];
    float* out = (float*)d_out;
    float* acc = (float*)d_ws;

    zero_acc_kernel<<<1, 64, 0, stream>>>(acc);

    dim3 grid(BLOCKS_PER_IMG, BATCH);   // 48 x 16 = 768 blocks, 2304 waves
    lncc4<<<grid, NTHREADS, 0, stream>>>(I, J, acc);

    finalize_kernel<<<1, 64, 0, stream>>>(acc, out);
}